// Round 1
// 174.154 us; speedup vs baseline: 1.1105x; 1.1105x over previous
//
#include <hip/hip_runtime.h>
#include <stdint.h>
#include <math.h>

#define T_STEPS 4096
#define BATCH   256
#define NB_BLK  256      // T/16 spike blocks per chain == cert segments

// s_waitcnt immediates (gfx9 encoding): vmcnt[3:0]|expcnt[6:4]|lgkmcnt[11:8]|vmcnt[15:14]
#define WAIT_VM0   0x0F70   // vmcnt(0), expcnt/lgkmcnt unrestricted
#define WAIT_LGKM0 0xC07F   // lgkmcnt(0), vmcnt/expcnt unrestricted

// LIF step, threshold=1:  v'=alpha*v+xs; s=max(floor(v'),0); v=v'-s
// Identity: v_new = min(v', fract(v')); s = v' - v_new (exact fp32).
// No-spike step (0<=v'<1 or v'<0) is EXACTLY v = fma(alpha, v, xs).
__device__ __forceinline__ float lif_step(float& v, float xs, float alpha) {
    float vp = fmaf(alpha, v, xs);
    float fr = vp - floorf(vp);
    float vn = fminf(vp, fr);
    float s  = vp - vn;
    v = vn;
    return s;
}

__device__ __forceinline__ float ubf(uint32_t w, int k) {
    return (float)((w >> (k * 8)) & 0xffu);
}

__device__ __forceinline__ float dot16(const float wr[16],
    float4 c0, float4 c1, float4 c2, float4 c3)
{
    float p0 = fmaf(wr[1], c0.y, wr[0] * c0.x);
    p0 = fmaf(wr[2], c0.z, p0);  p0 = fmaf(wr[3], c0.w, p0);
    float p1 = fmaf(wr[5], c1.y, wr[4] * c1.x);
    p1 = fmaf(wr[6], c1.z, p1);  p1 = fmaf(wr[7], c1.w, p1);
    float p2 = fmaf(wr[9], c2.y, wr[8] * c2.x);
    p2 = fmaf(wr[10], c2.z, p2); p2 = fmaf(wr[11], c2.w, p2);
    float p3 = fmaf(wr[13], c3.y, wr[12] * c3.x);
    p3 = fmaf(wr[14], c3.z, p3); p3 = fmaf(wr[15], c3.w, p3);
    return (p0 + p1) + (p2 + p3);
}

// Direct global->LDS DMA, 16 B per lane, no VGPR round-trip (R12: killed the
// 60-130 MB scratch-spill traffic of R9-R11).
__device__ __forceinline__ void load_lds16(const float* g, float* l) {
    __builtin_amdgcn_global_load_lds(
        (const __attribute__((address_space(1))) void*)g,
        (__attribute__((address_space(3))) void*)l, 16, 0, 0);
}

// xbuf layout: segment s (16 rows x 16 floats) at float offset s*260
// (1040 B pitch = 1024 B payload + 16 B pad).  A wave's global_load_lds
// fills exactly one segment (64 lanes x 16 B contiguous); the pad sits
// between transfers.  Compute: the 4 distinct sg-addresses in a wave are
// 260 floats apart (bank offset 4) -> the 4 ds_read_b128 hit disjoint bank
// quads (co lanes broadcast) — conflict-free.
//
// KEY (R13): wave wv stages segments wv*4..wv*4+3 and its compute threads
// have sg = tid>>4 in exactly {wv*4..wv*4+3} — LDS regions are WAVE-PRIVATE.
// So the k-loop needs NO __syncthreads at all: wave-local s_waitcnt vmcnt(0)
// after DMA (data landed) and lgkmcnt(0) before re-DMA (reads drained).
//
// R14: repair parallelized.  Old path: while(badmask) handled ONE channel per
// iteration with a block-wide y-recompute + 2 barriers + a tid==0 serial scan
// of ALL 4096 steps (~7 us per channel, serialized) — that was the 88 us
// critical path (VALUBusy 13%, occupancy 14%: tail blocks).  New path: wave wv
// repairs the wv-th bad channel CONCURRENTLY; cert-good segments compose with
// a single fma jump v = fma(alpha16, v, sh_end[s][c]) (sh_end already in LDS);
// only cert-bad segments run the exact 16-step lif scan, re-reading their x
// rows from global (L2/L3-resident).  Jump error ~1e-6 << the 1e-3 guard band
// the certification already budgets (vs+1e-3, bound>=0.999).

// ---------------------------------------------------------------------------
__global__ __launch_bounds__(1024) void seg1(
    const float* __restrict__ x, const float* __restrict__ w1,
    float* __restrict__ out, uint8_t* __restrict__ s1t,
    uint8_t* __restrict__ bm1, uint8_t* __restrict__ bm2,
    uint8_t* __restrict__ flag1, uint8_t* __restrict__ flag2,
    float alpha, float one_m, float alpha16)
{
    const int tid = threadIdx.x;
    const int b   = blockIdx.x;

    __shared__ __align__(16) float xbuf[16640];          // 65 KiB (chunk buf)
    __shared__ float   sh_end[NB_BLK][16];               // 16 KiB
    __shared__ float   sh_m0[NB_BLK][16];
    __shared__ float   sh_m1[NB_BLK][16];
    __shared__ uint8_t sh_badseg[16][NB_BLK];            // 4 KiB
    __shared__ int     sh_badch;
    __shared__ int     sh_spike;

    const int co = tid & 15;
    const int sg = tid >> 4;          // 0..63 segment-within-chunk
    const int wv = tid >> 6;          // wave 0..15
    const int ln = tid & 63;          // lane 0..63

    const float* xb = x + (size_t)b * T_STEPS * 16;      // 65536 floats

    // ---- kick off chunk 0 DMA immediately ---------------------------------
#pragma unroll
    for (int q = 0; q < 4; ++q) {
        int s = wv * 4 + q;
        load_lds16(xb + (size_t)s * 256 + ln * 4, &xbuf[s * 260 + ln * 4]);
    }

    // ---- zero per-batch slices (overlaps with chunk-0 DMA) ----------------
    float4* o4 = (float4*)(out + (size_t)b * T_STEPS * 10);   // 10240 float4
    float4 z4 = make_float4(0.f, 0.f, 0.f, 0.f);
#pragma unroll
    for (int i = 0; i < 10; ++i) o4[i * 1024 + tid] = z4;
    if (tid < 16)
        ((uint4*)(bm1 + (size_t)b * NB_BLK))[tid] = make_uint4(0u,0u,0u,0u);
    else if (tid < 32)
        ((uint4*)(bm2 + (size_t)b * NB_BLK))[tid - 16] = make_uint4(0u,0u,0u,0u);
    else if (tid == 32) { flag2[b] = 0; sh_badch = 0; sh_spike = 0; }

    float wr[16];
#pragma unroll
    for (int i = 0; i < 16; ++i) wr[i] = one_m * w1[co * 16 + i];

    const int sbase = sg * 260;
    for (int k = 0; k < 4; ++k) {
        __builtin_amdgcn_s_waitcnt(WAIT_VM0);   // wave-local: chunk k landed

        float acc = 0.0f, m0 = -1e30f, m1 = -1e30f, pw = alpha;
#pragma unroll
        for (int j = 0; j < 16; ++j) {
            const float* rp = &xbuf[sbase + j * 16];
            float4 c0 = *(const float4*)(rp + 0);
            float4 c1 = *(const float4*)(rp + 4);
            float4 c2 = *(const float4*)(rp + 8);
            float4 c3 = *(const float4*)(rp + 12);
            float y = dot16(wr, c0, c1, c2, c3);
            acc = fmaf(alpha, acc, y);
            m0  = fmaxf(m0, acc);
            m1  = fmaxf(m1, acc + pw);
            pw *= alpha;
        }
        const int gs = k * 64 + sg;
        sh_end[gs][co] = acc;
        sh_m0[gs][co]  = m0;
        sh_m1[gs][co]  = m1;

        if (k < 3) {
            // wave-local: all our ds_reads of this chunk are complete
            __builtin_amdgcn_s_waitcnt(WAIT_LGKM0);
#pragma unroll
            for (int q = 0; q < 4; ++q) {
                int s = wv * 4 + q;
                load_lds16(xb + (size_t)((k + 1) * 64 + s) * 256 + ln * 4,
                           &xbuf[s * 260 + ln * 4]);
            }
        }
    }
    __syncthreads();   // all waves' cert entries visible

    // ---- serial composition + per-channel/per-segment certification -------
    if (tid < 16) {
        const int c = tid;
        float vs = 0.0f;
        int bad = 0;
#pragma unroll 8
        for (int s = 0; s < NB_BLK; ++s) {
            float vsu = fminf(fmaxf(vs + 1e-3f, 0.0f), 1.0f);
            float bound = fmaf(1.0f - vsu, sh_m0[s][c], vsu * sh_m1[s][c]);
            int sb = (bound >= 0.999f) ? 1 : 0;
            sh_badseg[c][s] = (uint8_t)sb;
            bad |= sb;
            vs = fmaf(alpha16, vs, sh_end[s][c]);
        }
        if (bad) atomicOr(&sh_badch, 1 << c);
    }
    __syncthreads();

    // ---- parallel repair for cert-bad channels (rare) ---------------------
    const int badmask = sh_badch;
    if (badmask) {
        // dense-zero s1t[b] so scan2 never reads unwritten bytes
        uint4* sz = (uint4*)(s1t + (size_t)b * 16 * T_STEPS);
#pragma unroll
        for (int i = 0; i < 4; ++i) sz[i * 1024 + tid] = make_uint4(0u,0u,0u,0u);
        __syncthreads();   // zeroing ordered before repair spike writes

        // wave wv repairs the wv-th set bit of badmask (one lane per wave;
        // different channels -> disjoint s1t rows; bm1[s]=1 byte races are
        // same-value benign).
        int m = badmask;
        for (int i = 0; i < wv; ++i) m &= m - 1;
        if (ln == 0 && m) {
            const int c = __ffs(m) - 1;
            float wc[16];
#pragma unroll
            for (int i = 0; i < 16; ++i) wc[i] = one_m * w1[c * 16 + i];
            uint8_t* op  = s1t + ((size_t)b * 16 + c) * T_STEPS;
            uint8_t* bmp = bm1 + (size_t)b * NB_BLK;
            const uint8_t* bs = &sh_badseg[c][0];
            float v = 0.0f;
            int any = 0;
            for (int s = 0; s < NB_BLK; ++s) {
                if (!bs[s]) {
                    // cert-good: no spike possible; linear jump across the
                    // 16-step segment via its zero-state response (in LDS).
                    v = fmaf(alpha16, v, sh_end[s][c]);
                } else {
                    // exact 16-step lif scan; y recomputed from global x
                    const float4* xq = (const float4*)xb + (size_t)s * 64;
                    uint32_t w[4] = {0u,0u,0u,0u};
#pragma unroll 4
                    for (int j = 0; j < 16; ++j) {
                        float4 c0 = xq[j*4+0], c1 = xq[j*4+1];
                        float4 c2 = xq[j*4+2], c3 = xq[j*4+3];
                        float y  = dot16(wc, c0, c1, c2, c3);
                        float sp = lif_step(v, y, alpha);
                        w[j >> 2] |= ((uint32_t)(int)sp) << ((j & 3) * 8);
                    }
                    if (w[0] | w[1] | w[2] | w[3]) {
                        *(uint4*)(op + s * 16) = make_uint4(w[0], w[1], w[2], w[3]);
                        bmp[s] = 1;
                        any = 1;
                    }
                }
            }
            if (any) sh_spike = 1;
        }
        __syncthreads();
    }
    if (tid == 0) flag1[b] = (uint8_t)sh_spike;
}

// ---------------- layer-2: sparse scan, s1t -> s2t + bitmap2 ----------------
__global__ __launch_bounds__(64) void scan2(const uint8_t* __restrict__ s1t,
        const float* __restrict__ w2, uint8_t* __restrict__ s2t,
        const uint8_t* __restrict__ bm1, uint8_t* __restrict__ bm2,
        const uint8_t* __restrict__ flag1, uint8_t* __restrict__ flag2,
        float alpha, float one_m)
{
    const int tid = threadIdx.x;
    const int co  = tid & 31;
    const int b   = blockIdx.x * 2 + (tid >> 5);
    if (!flag1[b]) return;   // no layer-1 spikes in this batch -> all zero

    float wr[16];
#pragma unroll
    for (int i = 0; i < 16; ++i) wr[i] = one_m * w2[co * 16 + i];

    const uint8_t* sbase = s1t + (size_t)b * 16 * T_STEPS;
    uint4* op = (uint4*)(s2t + ((size_t)b * 32 + co) * T_STEPS);
    const uint4* bmv = (const uint4*)(bm1 + (size_t)b * NB_BLK);
    uint8_t* bm2p = bm2 + (size_t)b * NB_BLK;

    float v = 0.0f;
    for (int sb = 0; sb < 16; ++sb) {
        uint4 bm = bmv[sb];
        if ((bm.x | bm.y | bm.z | bm.w) == 0u) {
            if (v != 0.0f) {
                for (int blk = 0; blk < 16 && v != 0.0f; ++blk) {
#pragma unroll
                    for (int j = 0; j < 16; ++j) v *= alpha;
                }
            }
            continue;
        }
        for (int blk = 0; blk < 16; ++blk) {
            uint32_t d = (blk < 4) ? bm.x : (blk < 8) ? bm.y
                       : (blk < 12) ? bm.z : bm.w;
            uint32_t byte = (d >> ((blk & 3) * 8)) & 0xffu;
            if (byte == 0u) {
                if (v != 0.0f) {
#pragma unroll
                    for (int j = 0; j < 16; ++j) v *= alpha;
                }
                continue;
            }
            const int tb = sb * 16 + blk;
            const int t0 = tb * 16;
            uint4 S[16];
#pragma unroll
            for (int c = 0; c < 16; ++c)
                S[c] = *(const uint4*)(sbase + (size_t)c * T_STEPS + t0);
            uint32_t w[4] = {0u, 0u, 0u, 0u};
#pragma unroll
            for (int j = 0; j < 16; ++j) {
                float xv[16];
#pragma unroll
                for (int c = 0; c < 16; ++c) {
                    uint32_t dd = (j < 4) ? S[c].x : (j < 8) ? S[c].y
                                : (j < 12) ? S[c].z : S[c].w;
                    xv[c] = ubf(dd, j & 3);
                }
                float p0 = fmaf(wr[1], xv[1], wr[0] * xv[0]);
                p0 = fmaf(wr[2], xv[2], p0);   p0 = fmaf(wr[3], xv[3], p0);
                float p1 = fmaf(wr[5], xv[5], wr[4] * xv[4]);
                p1 = fmaf(wr[6], xv[6], p1);   p1 = fmaf(wr[7], xv[7], p1);
                float p2 = fmaf(wr[9], xv[9], wr[8] * xv[8]);
                p2 = fmaf(wr[10], xv[10], p2); p2 = fmaf(wr[11], xv[11], p2);
                float p3 = fmaf(wr[13], xv[13], wr[12] * xv[12]);
                p3 = fmaf(wr[14], xv[14], p3); p3 = fmaf(wr[15], xv[15], p3);
                float xs = (p0 + p1) + (p2 + p3);
                float s = lif_step(v, xs, alpha);
                w[j >> 2] |= ((uint32_t)(int)s) << ((j & 3) * 8);
            }
            op[tb] = make_uint4(w[0], w[1], w[2], w[3]);
            if (w[0] | w[1] | w[2] | w[3]) { bm2p[tb] = 1; flag2[b] = 1; }
        }
    }
}

// ---------------- layer-3: sparse scan, s2t -> out[b,t,10] (pre-zeroed) -----
__global__ __launch_bounds__(64) void scan3(const uint8_t* __restrict__ s2t,
        const float* __restrict__ w3, float* __restrict__ out,
        const uint8_t* __restrict__ bm2, const uint8_t* __restrict__ flag2,
        float alpha, float one_m)
{
    const int tid = threadIdx.x;
    const int co  = tid & 15;           // 10 active
    const int b   = blockIdx.x * 4 + (tid >> 4);
    if (!flag2[b]) return;   // no layer-2 spikes in this batch -> out stays 0
    const bool active = (co < 10);

    float wr[32];
#pragma unroll
    for (int i = 0; i < 32; ++i) wr[i] = active ? (one_m * w3[co * 32 + i]) : 0.0f;

    const uint8_t* sbase = s2t + (size_t)b * 32 * T_STEPS;
    const uint4* bmv = (const uint4*)(bm2 + (size_t)b * NB_BLK);
    float* ob = out + (size_t)b * T_STEPS * 10 + co;

    float v = 0.0f;
    for (int sb = 0; sb < 16; ++sb) {
        uint4 bm = bmv[sb];
        if ((bm.x | bm.y | bm.z | bm.w) == 0u) {
            if (v != 0.0f) {
                for (int blk = 0; blk < 16 && v != 0.0f; ++blk) {
#pragma unroll
                    for (int j = 0; j < 16; ++j) v *= alpha;
                }
            }
            continue;
        }
        for (int blk = 0; blk < 16; ++blk) {
            uint32_t d = (blk < 4) ? bm.x : (blk < 8) ? bm.y
                       : (blk < 12) ? bm.z : bm.w;
            uint32_t byte = (d >> ((blk & 3) * 8)) & 0xffu;
            if (byte == 0u) {
                if (v != 0.0f) {
#pragma unroll
                    for (int j = 0; j < 16; ++j) v *= alpha;
                }
                continue;
            }
            const int t0 = (sb * 16 + blk) * 16;
            uint4 S[32];
#pragma unroll
            for (int c = 0; c < 32; ++c)
                S[c] = *(const uint4*)(sbase + (size_t)c * T_STEPS + t0);
#pragma unroll
            for (int j = 0; j < 16; ++j) {
                float xv[32];
#pragma unroll
                for (int c = 0; c < 32; ++c) {
                    uint32_t dd = (j < 4) ? S[c].x : (j < 8) ? S[c].y
                                : (j < 12) ? S[c].z : S[c].w;
                    xv[c] = ubf(dd, j & 3);
                }
                float p0 = fmaf(wr[1], xv[1], wr[0] * xv[0]);
                p0 = fmaf(wr[2],  xv[2],  p0); p0 = fmaf(wr[3],  xv[3],  p0);
                p0 = fmaf(wr[4],  xv[4],  p0); p0 = fmaf(wr[5],  xv[5],  p0);
                p0 = fmaf(wr[6],  xv[6],  p0); p0 = fmaf(wr[7],  xv[7],  p0);
                float p1 = fmaf(wr[9], xv[9], wr[8] * xv[8]);
                p1 = fmaf(wr[10], xv[10], p1); p1 = fmaf(wr[11], xv[11], p1);
                p1 = fmaf(wr[12], xv[12], p1); p1 = fmaf(wr[13], xv[13], p1);
                p1 = fmaf(wr[14], xv[14], p1); p1 = fmaf(wr[15], xv[15], p1);
                float p2 = fmaf(wr[17], xv[17], wr[16] * xv[16]);
                p2 = fmaf(wr[18], xv[18], p2); p2 = fmaf(wr[19], xv[19], p2);
                p2 = fmaf(wr[20], xv[20], p2); p2 = fmaf(wr[21], xv[21], p2);
                p2 = fmaf(wr[22], xv[22], p2); p2 = fmaf(wr[23], xv[23], p2);
                float p3 = fmaf(wr[25], xv[25], wr[24] * xv[24]);
                p3 = fmaf(wr[26], xv[26], p3); p3 = fmaf(wr[27], xv[27], p3);
                p3 = fmaf(wr[28], xv[28], p3); p3 = fmaf(wr[29], xv[29], p3);
                p3 = fmaf(wr[30], xv[30], p3); p3 = fmaf(wr[31], xv[31], p3);
                float xs = (p0 + p1) + (p2 + p3);
                float s = lif_step(v, xs, alpha);
                if (active && s != 0.0f) ob[(size_t)(t0 + j) * 10] = s;
            }
        }
    }
}

extern "C" void kernel_launch(void* const* d_in, const int* in_sizes, int n_in,
                              void* d_out, int out_size, void* d_ws, size_t ws_size,
                              hipStream_t stream)
{
    const float* data = (const float*)d_in[0];
    const float* w1   = (const float*)d_in[1];
    const float* w2   = (const float*)d_in[2];
    const float* w3   = (const float*)d_in[3];
    float* out = (float*)d_out;

    // ws layout (48 MiB + 128 KiB + 512 B):
    //   [0, 16M)    s1t  u8 [256][16][4096]  (dense-zeroed only for flagged b)
    //   [16M, 48M)  s2t  u8 [256][32][4096]  (sparse: only bm2-set blocks valid)
    //   [48M, ..)   bm1 64K | bm2 64K | flag1 256 | flag2 256
    uint8_t* ws    = (uint8_t*)d_ws;
    uint8_t* s1t   = ws;
    uint8_t* s2t   = ws + (16u << 20);
    uint8_t* bm1   = ws + (48u << 20);
    uint8_t* bm2   = bm1 + (64u << 10);
    uint8_t* flag1 = bm2 + (64u << 10);
    uint8_t* flag2 = flag1 + 256;

    const float alpha   = expf(-1.0f / 20.0f);
    const float one_m   = 1.0f - alpha;
    const float alpha16 = expf(-16.0f / 20.0f);

    seg1 <<<BATCH,   1024, 0, stream>>>(data, w1, out, s1t, bm1, bm2,
                                        flag1, flag2, alpha, one_m, alpha16);
    scan2<<<BATCH/2,   64, 0, stream>>>(s1t, w2, s2t, bm1, bm2, flag1, flag2,
                                        alpha, one_m);
    scan3<<<BATCH/4,   64, 0, stream>>>(s2t, w3, out, bm2, flag2, alpha, one_m);
}